// Round 3
// baseline (78.058 us; speedup 1.0000x reference)
//
#include <hip/hip_runtime.h>
#include <hip/hip_bf16.h>

// Conv2dKan, fused MFMA kernel. b=16, cin=cout=64, H=W=32, K=3, PAD=1, BASIS=8.
// out[b,o,pix] = bias[o] + sum_{i,k,s8} Wt[i,k,o,s]*act(x[b,i,pix+off(k)])[s]
//   Wt[...,0]=w, Wt[...,s]=w*c[s] (s=1..7) bf16, layout [i][kpos][o][s]
//   act(x) = [silu(x), T1..T7(tanh x)] bf16; act(pad) = act(0) = [0,0,-1,0,1,0,-1,0]
//   bias[o] = sum_{i,k} w*c[...,0]  (T0==1)
// MFMA 16x16x32 bf16 (layouts HW-verified R3/R5): A/B: lane=(quad,l16), k=quad*8+s;
//   C/D: col=l16, row=quad*4+r.
// R19 = R18 compute structure + 8 WAVES/SIMD (2 blocks/CU):
//   R18 (74.1) was stall-bound: af-LDS floor ~8.7us/CU inflated to ~28us main at
//   4 w/SIMD. R19: grid 512 = 16b x 16rp x 2 o-halves, block 1024 (16 waves =
//   kq4 x oh2 x ph2, acc[2], wave = 32pix x 16o x 16ch).
//   - xlds DROPPED: every halo x value is consumed exactly once by act (kpos
//     reuse lives in the act scratch) -> LDS = 2 act bufs only = 69632 B ->
//     2 blocks/CU, 32 waves/CU. Act reads x straight from L2/L3 (warmed by
//     prep), borders via branchless 0 (act(0) == pad vector, rcp(2) exact).
//   - T14 prefetch: x-loads for chunk c+1 issue before the barrier, land under
//     MFMA(c). 8 w/SIMD TLP covers the rest.
//   - act recomputed per o-half (~1us VALU, +nothing on LDS); wf L2 aggregate
//     302 MB ~ 8.7us on the VMEM pipe, overlapped with the 8.7us af-LDS floor.
//   - __launch_bounds__(1024,8): VGPR cap 64 (est. peak ~40). Same-CU block
//     pairs are the two o-halves of one (b,rp) -> shared x reads hit L1.
//   Epilogue red[kq4][pix64][33] = 33792 B overlays buf0 only (chunk-3 MFMA
//   reads buf1; buf0 readers fenced by the chunk-3 act barrier).

#define CIN   64
#define COUT  64
#define HW    32
#define LL    1024
#define NS    8

typedef __attribute__((ext_vector_type(8))) short short8;
typedef __attribute__((ext_vector_type(4))) float f32x4;

// ws layout (bytes):
//   [0)       Wt    : 64*9*64*8 bf16 = 589824 B   ([i][kpos][o][s])
//   [589824)  bias  : 64 f32         = 256 B
//   [590080)  dummy : keep-alive sink for prefetch

__global__ void prep_kernel(const float* __restrict__ w,
                            const float* __restrict__ c,
                            __hip_bfloat16* __restrict__ Wt,
                            float* __restrict__ bias,
                            const float* __restrict__ x,
                            float* __restrict__ dummy) {
    const int bx = blockIdx.x;
    if (bx < 144) {
        // Wt part
        const int tid = bx * 256 + threadIdx.x;   // < 36864 = 64i*9k*64o
        const int i = tid / (9 * COUT);
        const int r = tid - i * 9 * COUT;
        const int k = r / COUT;
        const int o = r - k * COUT;
        const int widx = (i * COUT + o) * 9 + k;
        const float wv = w[widx];
        __hip_bfloat16* dst = Wt + (size_t)tid * NS;   // tid == (i*9+k)*64+o
        dst[0] = __float2bfloat16(wv);
#pragma unroll
        for (int s = 1; s < 8; ++s) dst[s] = __float2bfloat16(wv * c[widx * 8 + s]);
        return;
    }
    if (bx < 208) {
        // bias part: 64 blocks, one o each; 64-lane wave reduce over i.
        const int o = bx - 144;
        const int i = threadIdx.x;
        if (i >= 64) return;
        float v = 0.f;
#pragma unroll
        for (int k = 0; k < 9; ++k) {
            const int idx = (i * COUT + o) * 9 + k;
            v += w[idx] * c[idx * 8];
        }
#pragma unroll
        for (int off = 32; off > 0; off >>= 1) v += __shfl_down(v, off);
        if (i == 0) bias[o] = v;
        return;
    }
    // x-prefetch part: 1024 blocks, each touches one (b,ch) 4KB image -> L3/L2 warm.
    const int idx = bx - 208;          // [0,1024)
    const int r  = idx & 7;
    const int m  = idx >> 3;
    const int b  = r + 8 * (m & 1);
    const int ch = m >> 1;
    const float4 v = ((const float4*)(x + (size_t)(b * CIN + ch) * LL))[threadIdx.x];
    const float acc = v.x + v.y + v.z + v.w;
    if (acc == 1.0e-37f) dummy[threadIdx.x] = acc;   // keep-alive; never taken in practice
}

// grid (16 b, 16 row-pairs, 2 o-halves), block 1024 = 16 waves = (kq4 x oh2 x ph2).
// Wave: 32pix (1 row) x 16o x 16ch.
__global__ __launch_bounds__(1024, 8) void kan_fused_kernel(
        const float* __restrict__ x,
        const __hip_bfloat16* __restrict__ Wt,
        const float* __restrict__ bias,
        float* __restrict__ out) {
    // ushort units:
    //   [0,     17408): act scratch buf0 [kq4][pos136][ch4] x 16B  (34816 B)
    //   [17408, 34816): act scratch buf1
    // epilogue overlay: float red[kq4][pix64][o 33pad] = 33792 B (buf0 only)
    __shared__ __align__(16) unsigned short Wlds[34816];   // 69632 B -> 2 blocks/CU

    const int tid   = threadIdx.x;
    const int wv    = tid >> 6;       // 0..15
    const int lane  = tid & 63;
    const int quad  = lane >> 4;      // channel within 4-ch chunk
    const int l16   = lane & 15;
    const int kq    = wv >> 2;        // K-quarter: channels [kq*16, kq*16+16)
    const int wq    = wv & 3;         // act sub-split within kq
    const int oh    = wq & 1;         // o 16-slice within the block's 32-o half
    const int ph    = wq >> 1;        // pixel row (0/1) within the row-pair

    const int b    = blockIdx.x;
    const int row0 = blockIdx.y << 1; // first of the 2 output rows
    const int ohB  = blockIdx.z;      // block o-half: o in [ohB*32, ohB*32+32)

    const unsigned short* WtU = (const unsigned short*)Wt;

    // act cell ownership (per kq-chunk slice of 544 = 136pos x 4ch):
    //   cell0 = wq*64+lane, cell1 = cell0+256 (always valid);
    //   cell2 = 512+lane only for wq==0 && lane<32.
    const int cell0 = wq * 64 + lane;
    const int cell1 = cell0 + 256;
    const bool has2 = (wq == 0) & (lane < 32);
    const int cell2 = 512 + lane;

    // x load for one act cell of a given chunk (border -> 0.0, branchless value)
    auto loadx = [&](int cell, int chunk) -> float {
        const int ch  = cell & 3;
        const int pos = cell >> 2;        // 0..135
        const int r4  = pos / 34;         // halo row 0..3
        const int col = pos - r4 * 34;
        const int gy  = row0 - 1 + r4;
        const int gx  = col - 1;
        float v = 0.f;
        if ((unsigned)gy < 32u && (unsigned)gx < 32u)
            v = x[((size_t)(b * CIN + kq * 16 + chunk * 4 + ch) * HW + gy) * HW + gx];
        return v;
    };

    f32x4 acc[2];                     // [h pix-frag], 16 o per wave
    acc[0] = (f32x4){0.f, 0.f, 0.f, 0.f};
    acc[1] = (f32x4){0.f, 0.f, 0.f, 0.f};

    // T14 prefetch: chunk-0 x loads issue now
    float xv0 = loadx(cell0, 0);
    float xv1 = loadx(cell1, 0);
    float xv2 = has2 ? loadx(cell2, 0) : 0.f;

    for (int chunk = 0; chunk < 4; ++chunk) {
        unsigned short* usd = Wlds + (chunk & 1) * 17408 + kq * 4352;

        // ---- act: single-exp, pack 8 x bf16, store 16B/cell ----
        auto actstore = [&](int cell, float xvv) {
            const float e   = __expf(xvv);                         // one exp
            const float sig = e * __builtin_amdgcn_rcpf(1.f + e);
            const float res = xvv * sig;                           // silu
            const float t   = 1.f - 2.f * __builtin_amdgcn_rcpf(__builtin_fmaf(e, e, 1.f)); // tanh
            const float t2  = t + t;
            const float T2 = __builtin_fmaf(t2, t,  -1.f);
            const float T3 = __builtin_fmaf(t2, T2, -t);
            const float T4 = __builtin_fmaf(t2, T3, -T2);
            const float T5 = __builtin_fmaf(t2, T4, -T3);
            const float T6 = __builtin_fmaf(t2, T5, -T4);
            const float T7 = __builtin_fmaf(t2, T6, -T5);
            union { __hip_bfloat162 h2[4]; float4 f4; } U;
            U.h2[0] = __float22bfloat162_rn(make_float2(res, t));
            U.h2[1] = __float22bfloat162_rn(make_float2(T2, T3));
            U.h2[2] = __float22bfloat162_rn(make_float2(T4, T5));
            U.h2[3] = __float22bfloat162_rn(make_float2(T6, T7));
            *(float4*)(usd + cell * 8) = U.f4;
        };
        actstore(cell0, xv0);
        actstore(cell1, xv1);
        if (has2) actstore(cell2, xv2);

        // issue next chunk's x loads BEFORE the barrier -> land under MFMA
        if (chunk < 3) {
            xv0 = loadx(cell0, chunk + 1);
            xv1 = loadx(cell1, chunk + 1);
            xv2 = has2 ? loadx(cell2, chunk + 1) : 0.f;
        }
        __syncthreads();   // scratch buf[chunk&1] ready

        // ---- MFMA: af from shared scratch, wf from global L2 ----
        const unsigned short* wchunk = WtU +
            ((size_t)(kq * 16 + chunk * 4 + quad) * 9 * COUT + ohB * 32 + oh * 16 + l16) * NS;
#pragma unroll
        for (int kpos = 0; kpos < 9; ++kpos) {
            const int dy = kpos / 3 - 1, dx = kpos % 3 - 1;
            const int posb = (ph + dy + 1) * 34 + (dx + 1);
            short8 af0 = *(const short8*)(usd + ((posb      + l16) * 4 + quad) * 8);
            short8 af1 = *(const short8*)(usd + ((posb + 16 + l16) * 4 + quad) * 8);
            short8 wf = *(const short8*)(wchunk + kpos * COUT * NS);
            acc[0] = __builtin_amdgcn_mfma_f32_16x16x32_bf16(wf, af0, acc[0], 0, 0, 0);
            acc[1] = __builtin_amdgcn_mfma_f32_16x16x32_bf16(wf, af1, acc[1], 0, 0, 0);
        }
    }

    // ---- epilogue: reduce 4 K-quarters via padded LDS.
    //      red (33792B) overlays buf0 only; chunk-3 MFMA read buf1, and buf0
    //      readers (chunk-2 MFMA) were fenced by the chunk-3 act barrier. Each
    //      wave writes only its own acc after its own chunk-3 MFMA. ----
    float* red = (float*)Wlds;       // red[kq][pix64][33]
#pragma unroll
    for (int h = 0; h < 2; ++h)
#pragma unroll
        for (int r = 0; r < 4; ++r) {
            const int p = ph * 32 + h * 16 + l16;   // pixel 0..63 (2 rows x 32 cols)
            const int o = oh * 16 + quad * 4 + r;   // block-local o 0..31
            red[(kq * 64 + p) * 33 + o] = acc[h][r];
        }
    __syncthreads();

#pragma unroll
    for (int rep = 0; rep < 2; ++rep) {
        const int v = rep * 1024 + tid;   // 2048 = 64 pix x 32 o
        const int p = v & 63;
        const int o = v >> 6;             // block-local
        const float s = red[p * 33 + o] + red[(64 + p) * 33 + o]
                      + red[(128 + p) * 33 + o] + red[(192 + p) * 33 + o]
                      + bias[ohB * 32 + o];
        out[(size_t)(b * COUT + ohB * 32 + o) * LL + (row0 + (p >> 5)) * HW + (p & 31)] = s;
    }
}

extern "C" void kernel_launch(void* const* d_in, const int* in_sizes, int n_in,
                              void* d_out, int out_size, void* d_ws, size_t ws_size,
                              hipStream_t stream) {
    const float* x = (const float*)d_in[0];
    const float* w = (const float*)d_in[1];
    const float* c = (const float*)d_in[2];
    float* out = (float*)d_out;

    char* ws = (char*)d_ws;
    __hip_bfloat16* Wt    = (__hip_bfloat16*)(ws);
    float*          bias  = (float*)(ws + 589824);
    float*          dummy = (float*)(ws + 590080);

    // 144 Wt + 64 bias + 1024 x-prefetch = 1232 blocks, all parallel
    prep_kernel<<<1232, 256, 0, stream>>>(w, c, Wt, bias, x, dummy);
    kan_fused_kernel<<<dim3(16, 16, 2), 1024, 0, stream>>>(x, Wt, bias, out);
}

// Round 4
// 77.663 us; speedup vs baseline: 1.0051x; 1.0051x over previous
//
#include <hip/hip_runtime.h>
#include <hip/hip_bf16.h>

// Conv2dKan, fused MFMA kernel. b=16, cin=cout=64, H=W=32, K=3, PAD=1, BASIS=8.
// out[b,o,pix] = bias[o] + sum_{i,k,s8} Wt[i,k,o,s]*act(x[b,i,pix+off(k)])[s]
//   Wt[...,0]=w, Wt[...,s]=w*c[s] (s=1..7) bf16, layout [i][kpos][o][s]
//   act(x) = [silu(x), T1..T7(tanh x)] bf16; act(pad) = act(0) = [0,0,-1,0,1,0,-1,0]
//   bias[o] = sum_{i,k} w*c[...,0]  (T0==1)
// MFMA 16x16x32 bf16 (layouts HW-verified R3/R5): A/B: lane=(quad,l16), k=quad*8+s;
//   C/D: col=l16, row=quad*4+r.
// R20 = R16 memory map (78336 B: 3-row xlds halo + double-buffered act scratch,
//   all loads COALESCED) x 1024-thread blocks -> 8 waves/SIMD:
//   - R18 (74.1us) proved 4 w/SIMD >> 2 w/SIMD at fixed traffic. R19 (78.1)
//     proved occupancy gains are destroyed by uncoalesced per-lane x gathers
//     (cell=pos*4+ch -> consecutive lanes 4KB apart). The LDS x-stage is about
//     LOAD SHAPING, not reuse.
//   - R20: grid (16b x 32rows) = 512 blocks, block 1024 = 16 waves (kq4 x oq4),
//     wave = 32pix x 16o x 16ch, acc[2]. LDS 78336 B -> 2 blocks/CU ->
//     32 waves/CU = 8 w/SIMD, 2x R18's latency hiding, coalesced halo preload.
//   - acc[2]=8 VGPR; per kpos only af0/af1 + 1 wf -> fits the 64-VGPR cap of
//     __launch_bounds__(1024,8) (est. peak ~55).
//   xlds layout [ch][pos102] (stride 102 = 6 mod 32 -> <=2-way-ish = free).
//   Epilogue red[kq4][pix32][65] = 33280 B overlays xlds+buf0 only (not buf1).

#define CIN   64
#define COUT  64
#define HW    32
#define LL    1024
#define NS    8

typedef __attribute__((ext_vector_type(8))) short short8;
typedef __attribute__((ext_vector_type(4))) float f32x4;

// ws layout (bytes):
//   [0)       Wt    : 64*9*64*8 bf16 = 589824 B   ([i][kpos][o][s])
//   [589824)  bias  : 64 f32         = 256 B
//   [590080)  dummy : keep-alive sink for prefetch

__global__ void prep_kernel(const float* __restrict__ w,
                            const float* __restrict__ c,
                            __hip_bfloat16* __restrict__ Wt,
                            float* __restrict__ bias,
                            const float* __restrict__ x,
                            float* __restrict__ dummy) {
    const int bx = blockIdx.x;
    if (bx < 144) {
        // Wt part
        const int tid = bx * 256 + threadIdx.x;   // < 36864 = 64i*9k*64o
        const int i = tid / (9 * COUT);
        const int r = tid - i * 9 * COUT;
        const int k = r / COUT;
        const int o = r - k * COUT;
        const int widx = (i * COUT + o) * 9 + k;
        const float wv = w[widx];
        __hip_bfloat16* dst = Wt + (size_t)tid * NS;   // tid == (i*9+k)*64+o
        dst[0] = __float2bfloat16(wv);
#pragma unroll
        for (int s = 1; s < 8; ++s) dst[s] = __float2bfloat16(wv * c[widx * 8 + s]);
        return;
    }
    if (bx < 208) {
        // bias part: 64 blocks, one o each; 64-lane wave reduce over i.
        const int o = bx - 144;
        const int i = threadIdx.x;
        if (i >= 64) return;
        float v = 0.f;
#pragma unroll
        for (int k = 0; k < 9; ++k) {
            const int idx = (i * COUT + o) * 9 + k;
            v += w[idx] * c[idx * 8];
        }
#pragma unroll
        for (int off = 32; off > 0; off >>= 1) v += __shfl_down(v, off);
        if (i == 0) bias[o] = v;
        return;
    }
    // x-prefetch part: 1024 blocks, each touches one (b,ch) 4KB image -> L3/L2 warm.
    const int idx = bx - 208;          // [0,1024)
    const int r  = idx & 7;
    const int m  = idx >> 3;
    const int b  = r + 8 * (m & 1);
    const int ch = m >> 1;
    const float4 v = ((const float4*)(x + (size_t)(b * CIN + ch) * LL))[threadIdx.x];
    const float acc = v.x + v.y + v.z + v.w;
    if (acc == 1.0e-37f) dummy[threadIdx.x] = acc;   // keep-alive; never taken in practice
}

// grid (16 b, 32 rows), block 1024 = 16 waves = (kq4 x oq4).
// Wave: 32pix (1 row) x 16o x 16ch.
__global__ __launch_bounds__(1024, 8) void kan_fused_kernel(
        const float* __restrict__ x,
        const __hip_bfloat16* __restrict__ Wt,
        const float* __restrict__ bias,
        float* __restrict__ out) {
    // ushort units:
    //   [0,     13056): xlds  — float x[ch64][pos102] (zero-padded halo), 26112 B
    //   [13056, 26112): act scratch buf0 [kq4][pos102][ch4] x 16B
    //   [26112, 39168): act scratch buf1
    // epilogue overlay: float red[kq4][pix32][o 65pad] = 33280 B (xlds+buf0 only)
    __shared__ __align__(16) unsigned short Wlds[39168];   // 78336 B -> 2 blocks/CU

    const int tid   = threadIdx.x;
    const int wv    = tid >> 6;       // 0..15
    const int lane  = tid & 63;
    const int quad  = lane >> 4;      // channel within 4-ch chunk
    const int l16   = lane & 15;
    const int kq    = wv >> 2;        // K-quarter: channels [kq*16, kq*16+16)
    const int oq    = wv & 3;         // o-quarter: [oq*16, oq*16+16)

    const int b   = blockIdx.x;
    const int row = blockIdx.y;

    const unsigned short* WtU = (const unsigned short*)Wt;
    float* xf = (float*)Wlds;         // xlds

    // ---- preload x halo: 64ch x 3rows x 34cols = 6528 cells, coalesced ----
#pragma unroll
    for (int p = 0; p < 7; ++p) {
        const int cell = p * 1024 + tid;
        if (cell < 6528) {
            const int ch  = cell / 102;
            const int pos = cell - ch * 102;
            const int r3  = (pos >= 68) ? 2 : ((pos >= 34) ? 1 : 0);
            const int col = pos - r3 * 34;
            const int gy  = row - 1 + r3;
            const int gx  = col - 1;
            float v = 0.f;   // border -> x=0 -> act computes exactly the pad vector
            if ((unsigned)gy < 32u && (unsigned)gx < 32u)
                v = x[((size_t)(b * CIN + ch) * HW + gy) * HW + gx];
            xf[cell] = v;                             // cell == ch*102 + pos
        }
    }
    __syncthreads();

    f32x4 acc[2];                     // [h pix-frag], 16 o per wave
    acc[0] = (f32x4){0.f, 0.f, 0.f, 0.f};
    acc[1] = (f32x4){0.f, 0.f, 0.f, 0.f};

    for (int chunk = 0; chunk < 4; ++chunk) {
        const int chbase = kq * 16 + chunk * 4;
        unsigned short* usd = Wlds + 13056 + (chunk & 1) * 13056 + kq * 3264;

        // ---- act: oq-quads split 408 cells; BRANCHLESS, x from LDS, single exp ----
#pragma unroll
        for (int p = 0; p < 2; ++p) {
            const int cell = (p * 4 + oq) * 64 + lane;
            if (cell < 408) {
                const int ch  = cell & 3;          // interleaved layout [pos][ch]
                const int pos = cell >> 2;         // 0..101
                const float xv = xf[(chbase + ch) * 102 + pos];
                const float e   = __expf(xv);                         // one exp
                const float sig = e * __builtin_amdgcn_rcpf(1.f + e);
                const float res = xv * sig;                           // silu
                const float t   = 1.f - 2.f * __builtin_amdgcn_rcpf(__builtin_fmaf(e, e, 1.f)); // tanh
                const float t2  = t + t;
                const float T2 = __builtin_fmaf(t2, t,  -1.f);
                const float T3 = __builtin_fmaf(t2, T2, -t);
                const float T4 = __builtin_fmaf(t2, T3, -T2);
                const float T5 = __builtin_fmaf(t2, T4, -T3);
                const float T6 = __builtin_fmaf(t2, T5, -T4);
                const float T7 = __builtin_fmaf(t2, T6, -T5);
                union { __hip_bfloat162 h2[4]; float4 f4; } U;
                U.h2[0] = __float22bfloat162_rn(make_float2(res, t));
                U.h2[1] = __float22bfloat162_rn(make_float2(T2, T3));
                U.h2[2] = __float22bfloat162_rn(make_float2(T4, T5));
                U.h2[3] = __float22bfloat162_rn(make_float2(T6, T7));
                *(float4*)(usd + cell * 8) = U.f4;
            }
        }
        __syncthreads();   // scratch buf[chunk&1] ready; xlds reads done

        // ---- MFMA: af from shared scratch, wf from global L2 ----
        const unsigned short* wchunk = WtU +
            ((size_t)(chbase + quad) * 9 * COUT + (oq << 4) + l16) * NS;
#pragma unroll
        for (int kpos = 0; kpos < 9; ++kpos) {
            const int posb = (kpos / 3) * 34 + (kpos % 3);   // (dy+1)*34+(dx+1)
            short8 af0 = *(const short8*)(usd + ((posb      + l16) * 4 + quad) * 8);
            short8 af1 = *(const short8*)(usd + ((posb + 16 + l16) * 4 + quad) * 8);
            short8 wf = *(const short8*)(wchunk + kpos * COUT * NS);
            acc[0] = __builtin_amdgcn_mfma_f32_16x16x32_bf16(wf, af0, acc[0], 0, 0, 0);
            acc[1] = __builtin_amdgcn_mfma_f32_16x16x32_bf16(wf, af1, acc[1], 0, 0, 0);
        }
    }

    // ---- epilogue: reduce 4 K-quarters via padded LDS.
    //      red (33280B) overlays xlds+buf0 only; chunk-3 MFMA read buf1, and
    //      buf0/xlds readers were fenced by the chunk-3 act barrier. Each wave
    //      writes only its own acc after its own chunk-3 MFMA -> no extra
    //      barrier needed before the writes. ----
    float* red = (float*)Wlds;       // red[kq][pix32][65]
#pragma unroll
    for (int h = 0; h < 2; ++h)
#pragma unroll
        for (int r = 0; r < 4; ++r) {
            const int p = h * 16 + l16;             // pixel 0..31
            const int o = (oq << 4) + quad * 4 + r; // o 0..63
            red[(kq * 32 + p) * 65 + o] = acc[h][r];
        }
    __syncthreads();

#pragma unroll
    for (int rep = 0; rep < 2; ++rep) {
        const int v = rep * 1024 + tid;   // 2048 = 32 pix x 64 o
        const int p = v & 31;
        const int o = v >> 5;
        const float s = red[p * 65 + o] + red[(32 + p) * 65 + o]
                      + red[(64 + p) * 65 + o] + red[(96 + p) * 65 + o] + bias[o];
        out[(size_t)(b * COUT + o) * LL + row * HW + p] = s;
    }
}

extern "C" void kernel_launch(void* const* d_in, const int* in_sizes, int n_in,
                              void* d_out, int out_size, void* d_ws, size_t ws_size,
                              hipStream_t stream) {
    const float* x = (const float*)d_in[0];
    const float* w = (const float*)d_in[1];
    const float* c = (const float*)d_in[2];
    float* out = (float*)d_out;

    char* ws = (char*)d_ws;
    __hip_bfloat16* Wt    = (__hip_bfloat16*)(ws);
    float*          bias  = (float*)(ws + 589824);
    float*          dummy = (float*)(ws + 590080);

    // 144 Wt + 64 bias + 1024 x-prefetch = 1232 blocks, all parallel
    prep_kernel<<<1232, 256, 0, stream>>>(w, c, Wt, bias, x, dummy);
    kan_fused_kernel<<<dim3(16, 32), 1024, 0, stream>>>(x, Wt, bias, out);
}

// Round 5
// 76.197 us; speedup vs baseline: 1.0244x; 1.0192x over previous
//
#include <hip/hip_runtime.h>
#include <hip/hip_bf16.h>

// Conv2dKan, fused MFMA kernel. b=16, cin=cout=64, H=W=32, K=3, PAD=1, BASIS=8.
// out[b,o,pix] = bias[o] + sum_{i,k,s8} Wt[i,k,o,s]*act(x[b,i,pix+off(k)])[s]
//   Wt[...,0]=w, Wt[...,s]=w*c[s] (s=1..7) bf16, layout [i][kpos][o][s]
//   act(x) = [silu(x), T1..T7(tanh x)] bf16; act(pad) = act(0) = [0,0,-1,0,1,0,-1,0]
//   bias[o] = sum_{i,k} w*c[...,0]  (T0==1)
// R21 = R18 dispatch shape (grid 16x16 row-pairs, 1024thr, 16 waves/CU — the
//   measured occupancy sweet spot; 147MB Wt stream) + 32x32x16 MFMA to cut the
//   dominant pipe, the af-LDS stream (was ~12us of ~25us main):
//   - MFMA 32x32x16: 16K MACs per 1KB af read (2x of 16x16x32), and each wave
//     owns BOTH 32-o tiles (acc0/acc1) -> one af feeds 2 MFMAs.
//     af reads/block: 2304 -> 576 (2.36 MB -> 0.59 MB). MFMA count 2304->1152.
//   - waves = kq8 x pm2: wave = 32pix(1 row) x 64o x 8ch. Per chunk each wave
//     contracts one K-step (2ch x 8s = K16) x 9 kpos.
//   - 32x32 layouts: C/D col=lane&31(pix), row=(reg&3)+8*(reg>>2)+4*(lane>>5)
//     (HW-verified per guide m74/m101); A row=lane&31(o), k=(lane>>5)*8+s;
//     B col=lane&31(pix), k=(lane>>5)*8+s (analog of R3/R5-verified 16x16 map).
//   - act scratch buf layout [kq8][pos136][chl2] x16B: af read = contiguous-1024B
//     permutation (conflict-free); act writes contiguous; 34816 B/buf, dbuf.
//   - xlds [ch64][pos136] f32 4-row halo, coalesced preload (load shaping).
//   LDS 104448 B -> 1 block/CU, 16 waves/CU. Epilogue: 8 kq-partials reduced in
//   2 o-rounds via red[kq8][pix64][33] = 67584 B overlaying xlds+buf0 only.

#define CIN   64
#define COUT  64
#define HW    32
#define LL    1024
#define NS    8

typedef __attribute__((ext_vector_type(8))) short short8;
typedef __attribute__((ext_vector_type(16))) float f32x16;

// ws layout (bytes):
//   [0)       Wt    : 64*9*64*8 bf16 = 589824 B   ([i][kpos][o][s])
//   [589824)  bias  : 64 f32         = 256 B
//   [590080)  dummy : keep-alive sink for prefetch

__global__ void prep_kernel(const float* __restrict__ w,
                            const float* __restrict__ c,
                            __hip_bfloat16* __restrict__ Wt,
                            float* __restrict__ bias,
                            const float* __restrict__ x,
                            float* __restrict__ dummy) {
    const int bx = blockIdx.x;
    if (bx < 144) {
        // Wt part
        const int tid = bx * 256 + threadIdx.x;   // < 36864 = 64i*9k*64o
        const int i = tid / (9 * COUT);
        const int r = tid - i * 9 * COUT;
        const int k = r / COUT;
        const int o = r - k * COUT;
        const int widx = (i * COUT + o) * 9 + k;
        const float wv = w[widx];
        __hip_bfloat16* dst = Wt + (size_t)tid * NS;   // tid == (i*9+k)*64+o
        dst[0] = __float2bfloat16(wv);
#pragma unroll
        for (int s = 1; s < 8; ++s) dst[s] = __float2bfloat16(wv * c[widx * 8 + s]);
        return;
    }
    if (bx < 208) {
        // bias part: 64 blocks, one o each; 64-lane wave reduce over i.
        const int o = bx - 144;
        const int i = threadIdx.x;
        if (i >= 64) return;
        float v = 0.f;
#pragma unroll
        for (int k = 0; k < 9; ++k) {
            const int idx = (i * COUT + o) * 9 + k;
            v += w[idx] * c[idx * 8];
        }
#pragma unroll
        for (int off = 32; off > 0; off >>= 1) v += __shfl_down(v, off);
        if (i == 0) bias[o] = v;
        return;
    }
    // x-prefetch part: 1024 blocks, each touches one (b,ch) 4KB image -> L3/L2 warm.
    const int idx = bx - 208;          // [0,1024)
    const int r  = idx & 7;
    const int m  = idx >> 3;
    const int b  = r + 8 * (m & 1);
    const int ch = m >> 1;
    const float4 v = ((const float4*)(x + (size_t)(b * CIN + ch) * LL))[threadIdx.x];
    const float acc = v.x + v.y + v.z + v.w;
    if (acc == 1.0e-37f) dummy[threadIdx.x] = acc;   // keep-alive; never taken in practice
}

// grid (16 b, 16 row-pairs), block 1024 = 16 waves = (kq8 x pm2).
// Wave: 32pix (1 row) x 64o (acc0: o<32, acc1: o>=32) x 8ch.
__global__ __launch_bounds__(1024, 4) void kan_fused_kernel(
        const float* __restrict__ x,
        const __hip_bfloat16* __restrict__ Wt,
        const float* __restrict__ bias,
        float* __restrict__ out) {
    // ushort units:
    //   [0,     17408): xlds  — float x[ch64][pos136] (zero-padded 4x34 halo), 34816 B
    //   [17408, 34816): act scratch buf0 [kq8][pos136][chl2] x 16B
    //   [34816, 52224): act scratch buf1
    // epilogue overlay: float red[kq8][pix64][o 33pad] = 67584 B (xlds+buf0 only)
    __shared__ __align__(16) unsigned short Wlds[52224];   // 104448 B -> 1 block/CU

    const int tid  = threadIdx.x;
    const int wv   = tid >> 6;        // 0..15
    const int lane = tid & 63;
    const int l31  = lane & 31;
    const int half = lane >> 5;       // K-step channel half / o-row group
    const int kq   = wv >> 1;         // K-eighth: channels [kq*8, kq*8+8)
    const int pm   = wv & 1;          // pixel row (0/1) within the row-pair

    const int b    = blockIdx.x;
    const int row0 = blockIdx.y << 1; // first of the 2 output rows

    const unsigned short* WtU = (const unsigned short*)Wt;
    float* xf = (float*)Wlds;         // xlds

    // ---- preload x halo: 64ch x 4rows x 34cols = 8704 cells, coalesced ----
#pragma unroll
    for (int p = 0; p < 9; ++p) {
        const int cell = p * 1024 + tid;
        if (cell < 8704) {
            const int ch  = cell / 136;
            const int pos = cell - ch * 136;
            const int r4  = pos / 34;                 // halo row 0..3
            const int col = pos - r4 * 34;
            const int gy  = row0 - 1 + r4;
            const int gx  = col - 1;
            float v = 0.f;   // border -> x=0 -> act computes exactly the pad vector
            if ((unsigned)gy < 32u && (unsigned)gx < 32u)
                v = x[((size_t)(b * CIN + ch) * HW + gy) * HW + gx];
            xf[cell] = v;                             // cell == ch*136 + pos
        }
    }
    __syncthreads();

    f32x16 acc0, acc1;                // o-tiles [0,32) and [32,64)
#pragma unroll
    for (int r = 0; r < 16; ++r) { acc0[r] = 0.f; acc1[r] = 0.f; }

    // lane-invariant part of the Wt address: ch = kq*8 + chunk*2 + half
    const size_t wlane = ((size_t)(kq * 8 + half) * 9 * 64 + l31) * 8;

    for (int chunk = 0; chunk < 4; ++chunk) {
        unsigned short* ubuf = Wlds + 17408 + (chunk & 1) * 17408;

        // ---- act: 2176 cells (16 ch x 136 pos); cells tid, tid+1024, tid+2048<128.
        //      cell = kqc*272 + pos*2 + chl, channel = kqc*8 + chunk*2 + chl ----
        auto doCell = [&](int cell) {
            const int kqc = cell / 272;
            const int rr  = cell - kqc * 272;
            const int chl = rr & 1;
            const int pos = rr >> 1;                 // 0..135
            const float xv = xf[(kqc * 8 + chunk * 2 + chl) * 136 + pos];
            const float e   = __expf(xv);                         // one exp
            const float sig = e * __builtin_amdgcn_rcpf(1.f + e);
            const float res = xv * sig;                           // silu
            const float t   = 1.f - 2.f * __builtin_amdgcn_rcpf(__builtin_fmaf(e, e, 1.f)); // tanh
            const float t2  = t + t;
            const float T2 = __builtin_fmaf(t2, t,  -1.f);
            const float T3 = __builtin_fmaf(t2, T2, -t);
            const float T4 = __builtin_fmaf(t2, T3, -T2);
            const float T5 = __builtin_fmaf(t2, T4, -T3);
            const float T6 = __builtin_fmaf(t2, T5, -T4);
            const float T7 = __builtin_fmaf(t2, T6, -T5);
            union { __hip_bfloat162 h2[4]; float4 f4; } U;
            U.h2[0] = __float22bfloat162_rn(make_float2(res, t));
            U.h2[1] = __float22bfloat162_rn(make_float2(T2, T3));
            U.h2[2] = __float22bfloat162_rn(make_float2(T4, T5));
            U.h2[3] = __float22bfloat162_rn(make_float2(T6, T7));
            *(float4*)(ubuf + cell * 8) = U.f4;
        };
        doCell(tid);
        doCell(tid + 1024);
        if (tid < 128) doCell(tid + 2048);

        __syncthreads();   // scratch buf[chunk&1] ready; xlds reads done

        // ---- MFMA: one K-step (2ch x 8s) x 9 kpos; af feeds both o-tiles ----
        const unsigned short* afb = ubuf + kq * 2176;          // [pos136][chl2] x 8
        const unsigned short* wc  = WtU + wlane + (size_t)chunk * 9216; // +2ch
#pragma unroll
        for (int kpos = 0; kpos < 9; ++kpos) {
            const int posb = (pm + kpos / 3) * 34 + (kpos % 3);
            short8 af  = *(const short8*)(afb + ((posb + l31) * 2 + half) * 8);
            short8 wf0 = *(const short8*)(wc + kpos * 512);
            short8 wf1 = *(const short8*)(wc + kpos * 512 + 256);
            acc0 = __builtin_amdgcn_mfma_f32_32x32x16_bf16(wf0, af, acc0, 0, 0, 0);
            acc1 = __builtin_amdgcn_mfma_f32_32x32x16_bf16(wf1, af, acc1, 0, 0, 0);
        }
    }

    // ---- epilogue: reduce 8 K-eighth partials, two o-rounds of 32.
    //      red (67584B) overlays xlds+buf0 only; chunk-3 MFMA read buf1, and
    //      xlds/buf0 readers were fenced by the chunk-3 act barrier. ----
    float* red = (float*)Wlds;       // red[kq8][pix64][33]
#pragma unroll
    for (int h = 0; h < 2; ++h) {
        if (h) __syncthreads();      // round-0 reads done before overwrite
        const f32x16 a = h ? acc1 : acc0;
#pragma unroll
        for (int r = 0; r < 16; ++r) {
            const int ol = (r & 3) + 8 * (r >> 2) + 4 * half;   // o within round
            red[(kq * 64 + pm * 32 + l31) * 33 + ol] = a[r];
        }
        __syncthreads();
#pragma unroll
        for (int rep = 0; rep < 2; ++rep) {
            const int v  = rep * 1024 + tid;   // 2048 = 64 pix x 32 o
            const int p  = v & 63;
            const int ol = v >> 6;
            float s = bias[h * 32 + ol];
#pragma unroll
            for (int kqq = 0; kqq < 8; ++kqq)
                s += red[(kqq * 64 + p) * 33 + ol];
            out[(size_t)(b * COUT + h * 32 + ol) * LL + (row0 + (p >> 5)) * HW + (p & 31)] = s;
        }
    }
}

extern "C" void kernel_launch(void* const* d_in, const int* in_sizes, int n_in,
                              void* d_out, int out_size, void* d_ws, size_t ws_size,
                              hipStream_t stream) {
    const float* x = (const float*)d_in[0];
    const float* w = (const float*)d_in[1];
    const float* c = (const float*)d_in[2];
    float* out = (float*)d_out;

    char* ws = (char*)d_ws;
    __hip_bfloat16* Wt    = (__hip_bfloat16*)(ws);
    float*          bias  = (float*)(ws + 589824);
    float*          dummy = (float*)(ws + 590080);

    // 144 Wt + 64 bias + 1024 x-prefetch = 1232 blocks, all parallel
    prep_kernel<<<1232, 256, 0, stream>>>(w, c, Wt, bias, x, dummy);
    kan_fused_kernel<<<dim3(16, 16), 1024, 0, stream>>>(x, Wt, bias, out);
}

// Round 6
// 74.922 us; speedup vs baseline: 1.0419x; 1.0170x over previous
//
#include <hip/hip_runtime.h>
#include <hip/hip_bf16.h>

// Conv2dKan, fused MFMA kernel. b=16, cin=cout=64, H=W=32, K=3, PAD=1, BASIS=8.
// out[b,o,pix] = bias[o] + sum_{i,k,s8} Wt[i,k,o,s]*act(x[b,i,pix+off(k)])[s]
//   Wt[...,0]=w, Wt[...,s]=w*c[s] (s=1..7) bf16, layout [i][kpos][o][s]
//   act(x) = [silu(x), T1..T7(tanh x)] bf16; act(pad) = act(0) = [0,0,-1,0,1,0,-1,0]
//   bias[o] = sum_{i,k} w*c[...,0]  (T0==1)
// R22 = R21 (32x32x16 MFMA, af-LDS stream quartered vs 16x16) with the wave
//   decomposition fixed from (kq8 x pm2) to (kq8 x om2):
//   - R21's pm-waves duplicated every Wt read -> 295MB aggregate L2 stream,
//     giving back the R16->R18-isolated -3.6us lever. R22: each wave owns ONE
//     o-tile and BOTH pixel rows; 8kq x 2om = 16 distinct (ch-pair, o-tile)
//     slices = Wt read EXACTLY ONCE per block (576KB -> 147MB aggregate).
//   - per chunk-kpos per wave: 1 wf load + 2 af loads (row0/row1) + 2 MFMA.
//     af reads/block = 1.18MB (still 2x less than R18's 2.36MB).
//   - 32x32 layouts (HW-verified by R21 pass): C/D col=lane&31(pix),
//     row=(reg&3)+8*(reg>>2)+4*(lane>>5); A row=lane&31(o), k=(lane>>5)*8+s;
//     B col=lane&31(pix), k=(lane>>5)*8+s.
//   - act scratch buf layout [kq8][pos136][chl2] x16B; dbuf, 1 barrier/chunk.
//   - xlds [ch64][pos136] f32 4-row halo, coalesced preload (load shaping).
//   LDS 104448 B -> 1 block/CU, 16 waves/CU (the measured occupancy plateau).
//   Epilogue: 8 kq-partials reduced in 2 o-rounds (round h written by om==h
//   waves) via red[kq8][pix64][33] = 67584 B overlaying xlds+buf0 only.

#define CIN   64
#define COUT  64
#define HW    32
#define LL    1024
#define NS    8

typedef __attribute__((ext_vector_type(8))) short short8;
typedef __attribute__((ext_vector_type(16))) float f32x16;

// ws layout (bytes):
//   [0)       Wt    : 64*9*64*8 bf16 = 589824 B   ([i][kpos][o][s])
//   [589824)  bias  : 64 f32         = 256 B
//   [590080)  dummy : keep-alive sink for prefetch

__global__ void prep_kernel(const float* __restrict__ w,
                            const float* __restrict__ c,
                            __hip_bfloat16* __restrict__ Wt,
                            float* __restrict__ bias,
                            const float* __restrict__ x,
                            float* __restrict__ dummy) {
    const int bx = blockIdx.x;
    if (bx < 144) {
        // Wt part
        const int tid = bx * 256 + threadIdx.x;   // < 36864 = 64i*9k*64o
        const int i = tid / (9 * COUT);
        const int r = tid - i * 9 * COUT;
        const int k = r / COUT;
        const int o = r - k * COUT;
        const int widx = (i * COUT + o) * 9 + k;
        const float wv = w[widx];
        __hip_bfloat16* dst = Wt + (size_t)tid * NS;   // tid == (i*9+k)*64+o
        dst[0] = __float2bfloat16(wv);
#pragma unroll
        for (int s = 1; s < 8; ++s) dst[s] = __float2bfloat16(wv * c[widx * 8 + s]);
        return;
    }
    if (bx < 208) {
        // bias part: 64 blocks, one o each; 64-lane wave reduce over i.
        const int o = bx - 144;
        const int i = threadIdx.x;
        if (i >= 64) return;
        float v = 0.f;
#pragma unroll
        for (int k = 0; k < 9; ++k) {
            const int idx = (i * COUT + o) * 9 + k;
            v += w[idx] * c[idx * 8];
        }
#pragma unroll
        for (int off = 32; off > 0; off >>= 1) v += __shfl_down(v, off);
        if (i == 0) bias[o] = v;
        return;
    }
    // x-prefetch part: 1024 blocks, each touches one (b,ch) 4KB image -> L3/L2 warm.
    const int idx = bx - 208;          // [0,1024)
    const int r  = idx & 7;
    const int m  = idx >> 3;
    const int b  = r + 8 * (m & 1);
    const int ch = m >> 1;
    const float4 v = ((const float4*)(x + (size_t)(b * CIN + ch) * LL))[threadIdx.x];
    const float acc = v.x + v.y + v.z + v.w;
    if (acc == 1.0e-37f) dummy[threadIdx.x] = acc;   // keep-alive; never taken in practice
}

// grid (16 b, 16 row-pairs), block 1024 = 16 waves = (kq8 x om2).
// Wave: 64pix (both rows) x 32o (tile om) x 8ch.
__global__ __launch_bounds__(1024, 4) void kan_fused_kernel(
        const float* __restrict__ x,
        const __hip_bfloat16* __restrict__ Wt,
        const float* __restrict__ bias,
        float* __restrict__ out) {
    // ushort units:
    //   [0,     17408): xlds  — float x[ch64][pos136] (zero-padded 4x34 halo), 34816 B
    //   [17408, 34816): act scratch buf0 [kq8][pos136][chl2] x 16B
    //   [34816, 52224): act scratch buf1
    // epilogue overlay: float red[kq8][pix64][o 33pad] = 67584 B (xlds+buf0 only)
    __shared__ __align__(16) unsigned short Wlds[52224];   // 104448 B -> 1 block/CU

    const int tid  = threadIdx.x;
    const int wv   = tid >> 6;        // 0..15
    const int lane = tid & 63;
    const int l31  = lane & 31;
    const int half = lane >> 5;       // K-step channel half
    const int kq   = wv >> 1;         // K-eighth: channels [kq*8, kq*8+8)
    const int om   = wv & 1;          // o-tile: [om*32, om*32+32)

    const int b    = blockIdx.x;
    const int row0 = blockIdx.y << 1; // first of the 2 output rows

    const unsigned short* WtU = (const unsigned short*)Wt;
    float* xf = (float*)Wlds;         // xlds

    // ---- preload x halo: 64ch x 4rows x 34cols = 8704 cells, coalesced ----
#pragma unroll
    for (int p = 0; p < 9; ++p) {
        const int cell = p * 1024 + tid;
        if (cell < 8704) {
            const int ch  = cell / 136;
            const int pos = cell - ch * 136;
            const int r4  = pos / 34;                 // halo row 0..3
            const int col = pos - r4 * 34;
            const int gy  = row0 - 1 + r4;
            const int gx  = col - 1;
            float v = 0.f;   // border -> x=0 -> act computes exactly the pad vector
            if ((unsigned)gy < 32u && (unsigned)gx < 32u)
                v = x[((size_t)(b * CIN + ch) * HW + gy) * HW + gx];
            xf[cell] = v;                             // cell == ch*136 + pos
        }
    }
    __syncthreads();

    f32x16 acc0, acc1;                // pixel rows 0 and 1 (same o-tile om)
#pragma unroll
    for (int r = 0; r < 16; ++r) { acc0[r] = 0.f; acc1[r] = 0.f; }

    // lane-invariant Wt base: ch = kq*8 + chunk*2 + half, o = om*32 + l31
    const size_t wlane = ((size_t)(kq * 8 + half) * 9 * 64 + om * 32 + l31) * 8;

    for (int chunk = 0; chunk < 4; ++chunk) {
        unsigned short* ubuf = Wlds + 17408 + (chunk & 1) * 17408;

        // ---- act: 2176 cells (16 ch x 136 pos); cells tid, tid+1024, tid+2048<128.
        //      cell = kqc*272 + pos*2 + chl, channel = kqc*8 + chunk*2 + chl ----
        auto doCell = [&](int cell) {
            const int kqc = cell / 272;
            const int rr  = cell - kqc * 272;
            const int chl = rr & 1;
            const int pos = rr >> 1;                 // 0..135
            const float xv = xf[(kqc * 8 + chunk * 2 + chl) * 136 + pos];
            const float e   = __expf(xv);                         // one exp
            const float sig = e * __builtin_amdgcn_rcpf(1.f + e);
            const float res = xv * sig;                           // silu
            const float t   = 1.f - 2.f * __builtin_amdgcn_rcpf(__builtin_fmaf(e, e, 1.f)); // tanh
            const float t2  = t + t;
            const float T2 = __builtin_fmaf(t2, t,  -1.f);
            const float T3 = __builtin_fmaf(t2, T2, -t);
            const float T4 = __builtin_fmaf(t2, T3, -T2);
            const float T5 = __builtin_fmaf(t2, T4, -T3);
            const float T6 = __builtin_fmaf(t2, T5, -T4);
            const float T7 = __builtin_fmaf(t2, T6, -T5);
            union { __hip_bfloat162 h2[4]; float4 f4; } U;
            U.h2[0] = __float22bfloat162_rn(make_float2(res, t));
            U.h2[1] = __float22bfloat162_rn(make_float2(T2, T3));
            U.h2[2] = __float22bfloat162_rn(make_float2(T4, T5));
            U.h2[3] = __float22bfloat162_rn(make_float2(T6, T7));
            *(float4*)(ubuf + cell * 8) = U.f4;
        };
        doCell(tid);
        doCell(tid + 1024);
        if (tid < 128) doCell(tid + 2048);

        __syncthreads();   // scratch buf[chunk&1] ready; xlds reads done

        // ---- MFMA: one K-step (2ch x 8s) x 9 kpos; wf read ONCE, feeds both rows ----
        const unsigned short* afb = ubuf + kq * 2176;          // [pos136][chl2] x 8
        const unsigned short* wc  = WtU + wlane + (size_t)chunk * 9216; // +2ch
#pragma unroll
        for (int kpos = 0; kpos < 9; ++kpos) {
            const int posb = (kpos / 3) * 34 + (kpos % 3);
            short8 af0 = *(const short8*)(afb + ((posb      + l31) * 2 + half) * 8);
            short8 af1 = *(const short8*)(afb + ((posb + 34 + l31) * 2 + half) * 8);
            short8 wf  = *(const short8*)(wc + kpos * 512);
            acc0 = __builtin_amdgcn_mfma_f32_32x32x16_bf16(wf, af0, acc0, 0, 0, 0);
            acc1 = __builtin_amdgcn_mfma_f32_32x32x16_bf16(wf, af1, acc1, 0, 0, 0);
        }
    }

    // ---- epilogue: reduce 8 K-eighth partials, two o-rounds of 32 (round h
    //      written by om==h waves; both accs = both pixel rows).
    //      red (67584B) overlays xlds+buf0 only; chunk-3 MFMA read buf1, and
    //      xlds/buf0 readers were fenced by the chunk-3 act barrier. ----
    float* red = (float*)Wlds;       // red[kq8][pix64][33]
#pragma unroll
    for (int h = 0; h < 2; ++h) {
        if (h) __syncthreads();      // round-0 reads done before overwrite
        if (om == h) {
#pragma unroll
            for (int r = 0; r < 16; ++r) {
                const int ol = (r & 3) + 8 * (r >> 2) + 4 * half;   // o within tile
                red[(kq * 64 +      l31) * 33 + ol] = acc0[r];      // row 0, pix 0..31
                red[(kq * 64 + 32 + l31) * 33 + ol] = acc1[r];      // row 1, pix 32..63
            }
        }
        __syncthreads();
#pragma unroll
        for (int rep = 0; rep < 2; ++rep) {
            const int v  = rep * 1024 + tid;   // 2048 = 64 pix x 32 o
            const int p  = v & 63;
            const int ol = v >> 6;
            float s = bias[h * 32 + ol];
#pragma unroll
            for (int kqq = 0; kqq < 8; ++kqq)
                s += red[(kqq * 64 + p) * 33 + ol];
            out[(size_t)(b * COUT + h * 32 + ol) * LL + (row0 + (p >> 5)) * HW + (p & 31)] = s;
        }
    }
}

extern "C" void kernel_launch(void* const* d_in, const int* in_sizes, int n_in,
                              void* d_out, int out_size, void* d_ws, size_t ws_size,
                              hipStream_t stream) {
    const float* x = (const float*)d_in[0];
    const float* w = (const float*)d_in[1];
    const float* c = (const float*)d_in[2];
    float* out = (float*)d_out;

    char* ws = (char*)d_ws;
    __hip_bfloat16* Wt    = (__hip_bfloat16*)(ws);
    float*          bias  = (float*)(ws + 589824);
    float*          dummy = (float*)(ws + 590080);

    // 144 Wt + 64 bias + 1024 x-prefetch = 1232 blocks, all parallel
    prep_kernel<<<1232, 256, 0, stream>>>(w, c, Wt, bias, x, dummy);
    kan_fused_kernel<<<dim3(16, 16), 1024, 0, stream>>>(x, Wt, bias, out);
}